// Round 11
// baseline (41.600 us; speedup 1.0000x reference)
//
#include <hip/hip_runtime.h>

// DRR via exact Siddon line integral — LDS tube staging.
// Block = 128 threads = 16x8 pixel patch x one depth chunk (1 thread = 1 ray).
// Grid = 200 tiles x 8 chunks; chunk in LOW 3 bits of blockIdx pins depth slab
// k to XCD k's L2 (round-robin dispatch). Each chunk walked in 4 stages; per
// stage the block computes the exact bounding box of all its segment-midpoint
// voxel indices (monotonicity of trunc(clamp(fma)) => endpoint box contains
// all midpoints), stages that box into LDS with coalesced float4 row loads,
// then gathers from LDS (ds_read ~10cy) instead of L1 (~55cy line-divergent).
static constexpr float F_SDD = 1020.0f;
static constexpr int   DH = 160, DW = 160;       // detector H, W
static constexpr float DELX = 2.5f, DELY = 2.5f;
static constexpr int   VOL = 256;                // volume is VOL^3
static constexpr int   NRAY = DH * DW;
static constexpr int   PX_T = 16, PY_T = 8;      // block pixel patch
static constexpr int   TILES_X = DW / PX_T;      // 10
static constexpr int   TILES_Y = DH / PY_T;      // 20
static constexpr int   NTILE = TILES_X * TILES_Y;// 200
static constexpr int   CHUNKS = 8;               // depth chunks (== XCD count)
static constexpr int   NSTG = 4;                 // stages per chunk
static constexpr int   KB = 4;                   // gather pipeline depth
static constexpr int   CAP_N0 = 22;              // tube capacity in i0-planes
static constexpr int   PLANE = 260;              // 16*16 + 4 pad floats (bank spread)
static constexpr float EPS = 1e-8f;

extern "C" __global__ void zero_out_kernel(float* __restrict__ out, int n) {
    int i = blockIdx.x * blockDim.x + threadIdx.x;
    if (i < n) out[i] = 0.0f;
}

extern "C" __global__ void __launch_bounds__(128)
drr_siddon_kernel(const float* __restrict__ density,
                  const float* __restrict__ pose,   // [4][4] row-major
                  const float* __restrict__ ainv,   // [4][4] row-major
                  float* __restrict__ out)          // [NRAY]
{
    __shared__ float tube[CAP_N0 * PLANE];          // 22.9 KB
    __shared__ float sb[2][6];                      // per-wave box partials

    int chunk = blockIdx.x & (CHUNKS - 1);          // low bits -> XCD id
    int tile  = blockIdx.x >> 3;                    // CHUNKS == 8
    int tx = tile % TILES_X, ty = tile / TILES_X;

    int tid = threadIdx.x;
    int px = tx * PX_T + (tid & 15);
    int py = ty * PY_T + (tid >> 4);
    int ray = py * DW + px;

    // Detector-plane target in camera frame (source at origin).
    float xs = ((float)px - (DW - 1) * 0.5f) * DELX;
    float ys = ((float)py - (DH - 1) * 0.5f) * DELY;

    // pose: rows of [R | t]
    float R00 = pose[0], R01 = pose[1], R02 = pose[2],  t0 = pose[3];
    float R10 = pose[4], R11 = pose[5], R12 = pose[6],  t1 = pose[7];
    float R20 = pose[8], R21 = pose[9], R22 = pose[10], t2 = pose[11];

    float sw0 = t0, sw1 = t1, sw2 = t2;                       // src_w = R*0 + t
    float tw0 = R00 * xs + R01 * ys + R02 * F_SDD + t0;
    float tw1 = R10 * xs + R11 * ys + R12 * F_SDD + t1;
    float tw2 = R20 * xs + R21 * ys + R22 * F_SDD + t2;

    float dw0 = tw0 - sw0, dw1 = tw1 - sw1, dw2 = tw2 - sw2;
    float raylen = sqrtf(dw0 * dw0 + dw1 * dw1 + dw2 * dw2);

    // world -> voxel
    float A00 = ainv[0], A01 = ainv[1], A02 = ainv[2],  A03 = ainv[3];
    float A10 = ainv[4], A11 = ainv[5], A12 = ainv[6],  A13 = ainv[7];
    float A20 = ainv[8], A21 = ainv[9], A22 = ainv[10], A23 = ainv[11];

    float s0 = A00 * sw0 + A01 * sw1 + A02 * sw2 + A03;
    float s1 = A10 * sw0 + A11 * sw1 + A12 * sw2 + A13;
    float s2 = A20 * sw0 + A21 * sw1 + A22 * sw2 + A23;
    float g0 = A00 * tw0 + A01 * tw1 + A02 * tw2 + A03;
    float g1 = A10 * tw0 + A11 * tw1 + A12 * tw2 + A13;
    float g2 = A20 * tw0 + A21 * tw1 + A22 * tw2 + A23;

    float sd0 = g0 - s0, sd1 = g1 - s1, sd2 = g2 - s2;
    float e0 = (fabsf(sd0) < EPS) ? EPS : sd0;
    float e1 = (fabsf(sd1) < EPS) ? EPS : sd1;
    float e2 = (fabsf(sd2) < EPS) ? EPS : sd2;
    float inv0 = 1.0f / e0, inv1 = 1.0f / e1, inv2 = 1.0f / e2;

    // bbox entry/exit in alpha, clamped to the [0,1] segment
    float lo0 = (0.0f - s0) * inv0, hi0 = ((float)VOL - s0) * inv0;
    float lo1 = (0.0f - s1) * inv1, hi1 = ((float)VOL - s1) * inv1;
    float lo2 = (0.0f - s2) * inv2, hi2 = ((float)VOL - s2) * inv2;
    float amin = fmaxf(fmaxf(fminf(lo0, hi0), fminf(lo1, hi1)), fminf(lo2, hi2));
    amin = fmaxf(amin, 0.0f);
    float amax = fminf(fminf(fmaxf(lo0, hi0), fmaxf(lo1, hi1)), fmaxf(lo2, hi2));
    amax = fminf(amax, 1.0f);
    amax = fmaxf(amax, amin);

    // chunk bounds: identical float math in every block of the same ray ->
    // exact cover across the 8 chunk-blocks.
    float arange  = amax - amin;
    float c_start = amin + arange * ((float)chunk * (1.0f / CHUNKS));
    float c_end   = (chunk == CHUNKS - 1) ? amax
                    : amin + arange * ((float)(chunk + 1) * (1.0f / CHUNKS));
    float crange  = c_end - c_start;

    float da0 = fabsf(inv0), da1 = fabsf(inv1), da2 = fabsf(inv2);

    float acc = 0.0f;

    for (int stg = 0; stg < NSTG; ++stg) {
        // stage sub-range (identical formulas -> exact cover within the chunk)
        float a0 = (stg == 0) ? c_start
                   : c_start + crange * ((float)stg * (1.0f / NSTG));
        float a1 = (stg == NSTG - 1) ? c_end
                   : c_start + crange * ((float)(stg + 1) * (1.0f / NSTG));

        // endpoint voxel coords with the SAME trunc(clamp(fma)) formula the
        // walk uses -> box provably contains every midpoint index.
        float qA0 = truncf(fminf(fmaxf(fmaf(a0, sd0, s0), 0.0f), 255.0f));
        float qA1 = truncf(fminf(fmaxf(fmaf(a0, sd1, s1), 0.0f), 255.0f));
        float qA2 = truncf(fminf(fmaxf(fmaf(a0, sd2, s2), 0.0f), 255.0f));
        float qB0 = truncf(fminf(fmaxf(fmaf(a1, sd0, s0), 0.0f), 255.0f));
        float qB1 = truncf(fminf(fmaxf(fmaf(a1, sd1, s1), 0.0f), 255.0f));
        float qB2 = truncf(fminf(fmaxf(fmaf(a1, sd2, s2), 0.0f), 255.0f));
        float l0 = fminf(qA0, qB0), h0 = fmaxf(qA0, qB0);
        float l1 = fminf(qA1, qB1), h1 = fmaxf(qA1, qB1);
        float l2 = fminf(qA2, qB2), h2 = fmaxf(qA2, qB2);
        for (int msk = 1; msk < 64; msk <<= 1) {
            l0 = fminf(l0, __shfl_xor(l0, msk));  h0 = fmaxf(h0, __shfl_xor(h0, msk));
            l1 = fminf(l1, __shfl_xor(l1, msk));  h1 = fmaxf(h1, __shfl_xor(h1, msk));
            l2 = fminf(l2, __shfl_xor(l2, msk));  h2 = fmaxf(h2, __shfl_xor(h2, msk));
        }
        if ((tid & 63) == 0) {
            int wv = tid >> 6;
            sb[wv][0] = l0; sb[wv][1] = h0; sb[wv][2] = l1;
            sb[wv][3] = h1; sb[wv][4] = l2; sb[wv][5] = h2;
        }
        __syncthreads();
        int b0  = (int)fminf(sb[0][0], sb[1][0]);
        int t0_ = (int)fmaxf(sb[0][1], sb[1][1]);
        int b1  = (int)fminf(sb[0][2], sb[1][2]);
        int t1_ = (int)fmaxf(sb[0][3], sb[1][3]);
        int b2  = (int)fminf(sb[0][4], sb[1][4]);
        int t2_ = (int)fmaxf(sb[0][5], sb[1][5]);
        int b2a = b2 & ~3;                          // 16B-align the i2 base
        int n0 = t0_ - b0 + 1;
        bool fits = (n0 <= CAP_N0) && (t1_ - b1 <= 15) && (t2_ - b2a <= 15);

        // per-stage axis walk init (R8-validated math)
        float ax0, ax1, ax2;
        if (fabsf(sd0) < EPS) ax0 = 3.0e38f;
        else { float p = s0 + a0 * sd0;
               float kk = (sd0 > 0.0f) ? (floorf(p) + 1.0f) : (ceilf(p) - 1.0f);
               ax0 = (kk - s0) * inv0; }
        if (fabsf(sd1) < EPS) ax1 = 3.0e38f;
        else { float p = s1 + a0 * sd1;
               float kk = (sd1 > 0.0f) ? (floorf(p) + 1.0f) : (ceilf(p) - 1.0f);
               ax1 = (kk - s1) * inv1; }
        if (fabsf(sd2) < EPS) ax2 = 3.0e38f;
        else { float p = s2 + a0 * sd2;
               float kk = (sd2 > 0.0f) ? (floorf(p) + 1.0f) : (ceilf(p) - 1.0f);
               ax2 = (kk - s2) * inv2; }

        if (fits) {
            // stage the tube: rows of 16 floats (i2), 16 i1 rows per i0 plane;
            // float4 loads (b2a 4-aligned; clamp keeps the quad in-bounds).
            int nq  = n0 << 6;                       // n0 * 64 quads
            int sk1 = t1_ - b1;
            for (int e = tid; e < nq; e += 128) {
                int q0 = e >> 6, rem = e & 63, q1 = rem >> 2, qc = (rem & 3) << 2;
                if (q1 <= sk1) {
                    int gz = min(b2a + qc, 252);
                    const float4 v = *(const float4*)(density +
                        (((b0 + q0) << 16) | ((b1 + q1) << 8) | gz));
                    *(float4*)(tube + (q0 * PLANE + (q1 << 4) + qc)) = v;
                }
            }
            __syncthreads();

            float Kf = (float)(b0 * PLANE + (b1 << 4) + b2a);
            float alpha = a0;
            while (alpha < a1) {
                float seg[KB]; float val[KB];
#pragma unroll
                for (int k = 0; k < KB; ++k) {
                    float m    = fminf(fminf(ax0, ax1), ax2);
                    float as_  = fminf(m, a1);
                    float amid = fminf(0.5f * (alpha + as_), a1); // stay in box
                    seg[k] = fmaxf(as_ - alpha, 0.0f);
                    float c0 = truncf(fminf(fmaxf(fmaf(amid, sd0, s0), 0.0f), 255.0f));
                    float c1 = truncf(fminf(fmaxf(fmaf(amid, sd1, s1), 0.0f), 255.0f));
                    float c2 = truncf(fminf(fmaxf(fmaf(amid, sd2, s2), 0.0f), 255.0f));
                    int li = (int)(fmaf(c0, (float)PLANE, fmaf(c1, 16.0f, c2)) - Kf);
                    val[k] = tube[li];               // LDS gather
                    if (ax0 <= m) ax0 += da0;
                    if (ax1 <= m) ax1 += da1;
                    if (ax2 <= m) ax2 += da2;
                    alpha = m;
                }
#pragma unroll
                for (int k = 0; k < KB; ++k) acc = fmaf(val[k], seg[k], acc);
            }
        } else {
            // rare fallback: identical walk, gathering from global (R10 path)
            float alpha = a0;
            while (alpha < a1) {
                float seg[KB]; float val[KB];
#pragma unroll
                for (int k = 0; k < KB; ++k) {
                    float m    = fminf(fminf(ax0, ax1), ax2);
                    float as_  = fminf(m, a1);
                    float amid = fminf(0.5f * (alpha + as_), a1);
                    seg[k] = fmaxf(as_ - alpha, 0.0f);
                    float c0 = truncf(fminf(fmaxf(fmaf(amid, sd0, s0), 0.0f), 255.0f));
                    float c1 = truncf(fminf(fmaxf(fmaf(amid, sd1, s1), 0.0f), 255.0f));
                    float c2 = truncf(fminf(fmaxf(fmaf(amid, sd2, s2), 0.0f), 255.0f));
                    int gi = (int)fmaf(c0, 65536.0f, fmaf(c1, 256.0f, c2));
                    val[k] = density[gi];
                    if (ax0 <= m) ax0 += da0;
                    if (ax1 <= m) ax1 += da1;
                    if (ax2 <= m) ax2 += da2;
                    alpha = m;
                }
#pragma unroll
                for (int k = 0; k < KB; ++k) acc = fmaf(val[k], seg[k], acc);
            }
        }
        __syncthreads();   // tube/sb safe to overwrite next stage
    }

    atomicAdd(&out[ray], acc * raylen);
}

extern "C" void kernel_launch(void* const* d_in, const int* in_sizes, int n_in,
                              void* d_out, int out_size, void* d_ws, size_t ws_size,
                              hipStream_t stream) {
    const float* density = (const float*)d_in[0];
    const float* pose    = (const float*)d_in[1];   // [1,4,4]
    const float* ainv    = (const float*)d_in[2];   // [4,4]
    float* out = (float*)d_out;                     // [1,1,160,160] flat

    hipLaunchKernelGGL(zero_out_kernel, dim3((NRAY + 255) / 256), dim3(256), 0,
                       stream, out, NRAY);

    dim3 block(128);
    dim3 grid(NTILE * CHUNKS);                      // 1600 blocks
    hipLaunchKernelGGL(drr_siddon_kernel, grid, block, 0, stream,
                       density, pose, ainv, out);
}

// Round 12
// 30.010 us; speedup vs baseline: 1.3862x; 1.3862x over previous
//
#include <hip/hip_runtime.h>

// DRR via exact Siddon line integral — R10 shell + per-lane float4 quad cache.
// Rays advance dominantly along i2 (stride-1 axis): consecutive segments
// usually hit the same aligned float4. Cache it per lane; select in-register
// on hit (3 cndmask), reload the aligned quad on miss (exec-masked, only
// missing lanes present addresses to the TA) -> ~2-3x fewer L1 transactions.
// Shell (R9/R10-validated): block = 256 threads = 4 waves; wave = 8x8 pixel
// patch at one of 4 alpha sub-ranges. Grid = 400 patches x 8 depth chunks;
// chunk in the LOW 3 bits of blockIdx pins depth slab k to XCD k's L2
// (round-robin dispatch). LDS-reduce -> 1 atomic per ray per block.
static constexpr float F_SDD = 1020.0f;
static constexpr int   DH = 160, DW = 160;       // detector H, W
static constexpr float DELX = 2.5f, DELY = 2.5f;
static constexpr int   VOL = 256;                // volume is VOL^3
static constexpr int   NRAY = DH * DW;
static constexpr int   TILES_X = DW / 8;         // 20
static constexpr int   TILES_Y = DH / 8;         // 20
static constexpr int   NTILE = TILES_X * TILES_Y;// 400
static constexpr int   CHUNKS = 8;               // depth chunks (== XCD count)
static constexpr int   SUBS = 4;                 // alpha sub-ranges (one per wave)
static constexpr float EPS = 1e-8f;

extern "C" __global__ void zero_out_kernel(float* __restrict__ out, int n) {
    int i = blockIdx.x * blockDim.x + threadIdx.x;
    if (i < n) out[i] = 0.0f;
}

extern "C" __global__ void __launch_bounds__(256)
drr_siddon_kernel(const float* __restrict__ density,
                  const float* __restrict__ pose,   // [4][4] row-major
                  const float* __restrict__ ainv,   // [4][4] row-major
                  float* __restrict__ out)          // [NRAY]
{
    __shared__ float red[256];

    int chunk = blockIdx.x & (CHUNKS - 1);          // low bits -> XCD id
    int tile  = blockIdx.x >> 3;                    // CHUNKS == 8
    int tx = tile % TILES_X, ty = tile / TILES_X;

    int tid  = threadIdx.x;
    int sub  = tid >> 6;                            // wave index = alpha quarter
    int lane = tid & 63;

    // wave = 8x8 pixel patch at one alpha sub-range: lanes are NEIGHBORING
    // rays at the SAME alpha -> coherent gathers (i2 is the 4B-stride axis).
    int px = tx * 8 + (lane & 7);
    int py = ty * 8 + (lane >> 3);
    int ray = py * DW + px;

    // Detector-plane target in camera frame (source at origin).
    float xs = ((float)px - (DW - 1) * 0.5f) * DELX;
    float ys = ((float)py - (DH - 1) * 0.5f) * DELY;

    // pose: rows of [R | t]
    float R00 = pose[0], R01 = pose[1], R02 = pose[2],  t0 = pose[3];
    float R10 = pose[4], R11 = pose[5], R12 = pose[6],  t1 = pose[7];
    float R20 = pose[8], R21 = pose[9], R22 = pose[10], t2 = pose[11];

    float sw0 = t0, sw1 = t1, sw2 = t2;                       // src_w = R*0 + t
    float tw0 = R00 * xs + R01 * ys + R02 * F_SDD + t0;
    float tw1 = R10 * xs + R11 * ys + R12 * F_SDD + t1;
    float tw2 = R20 * xs + R21 * ys + R22 * F_SDD + t2;

    float dw0 = tw0 - sw0, dw1 = tw1 - sw1, dw2 = tw2 - sw2;
    float raylen = sqrtf(dw0 * dw0 + dw1 * dw1 + dw2 * dw2);

    // world -> voxel
    float A00 = ainv[0], A01 = ainv[1], A02 = ainv[2],  A03 = ainv[3];
    float A10 = ainv[4], A11 = ainv[5], A12 = ainv[6],  A13 = ainv[7];
    float A20 = ainv[8], A21 = ainv[9], A22 = ainv[10], A23 = ainv[11];

    float s0 = A00 * sw0 + A01 * sw1 + A02 * sw2 + A03;
    float s1 = A10 * sw0 + A11 * sw1 + A12 * sw2 + A13;
    float s2 = A20 * sw0 + A21 * sw1 + A22 * sw2 + A23;
    float g0 = A00 * tw0 + A01 * tw1 + A02 * tw2 + A03;
    float g1 = A10 * tw0 + A11 * tw1 + A12 * tw2 + A13;
    float g2 = A20 * tw0 + A21 * tw1 + A22 * tw2 + A23;

    float sd0 = g0 - s0, sd1 = g1 - s1, sd2 = g2 - s2;
    float e0 = (fabsf(sd0) < EPS) ? EPS : sd0;
    float e1 = (fabsf(sd1) < EPS) ? EPS : sd1;
    float e2 = (fabsf(sd2) < EPS) ? EPS : sd2;
    float inv0 = 1.0f / e0, inv1 = 1.0f / e1, inv2 = 1.0f / e2;

    // bbox entry/exit in alpha, clamped to the [0,1] segment
    float lo0 = (0.0f - s0) * inv0, hi0 = ((float)VOL - s0) * inv0;
    float lo1 = (0.0f - s1) * inv1, hi1 = ((float)VOL - s1) * inv1;
    float lo2 = (0.0f - s2) * inv2, hi2 = ((float)VOL - s2) * inv2;
    float amin = fmaxf(fmaxf(fminf(lo0, hi0), fminf(lo1, hi1)), fminf(lo2, hi2));
    amin = fmaxf(amin, 0.0f);
    float amax = fminf(fminf(fmaxf(lo0, hi0), fmaxf(lo1, hi1)), fmaxf(lo2, hi2));
    amax = fminf(amax, 1.0f);
    amax = fmaxf(amax, amin);

    // chunk sub-range, then this wave's exact quarter. Identical float math in
    // every block/thread of the same ray -> exact cover (no gaps/overlap).
    float arange  = amax - amin;
    float c_start = amin + arange * ((float)chunk * (1.0f / CHUNKS));
    float c_end   = (chunk == CHUNKS - 1) ? amax
                    : amin + arange * ((float)(chunk + 1) * (1.0f / CHUNKS));
    float crange  = c_end - c_start;
    float a_start = c_start + crange * ((float)sub * (1.0f / SUBS));
    float a_end   = (sub == SUBS - 1) ? c_end
                    : c_start + crange * ((float)(sub + 1) * (1.0f / SUBS));

    // per-axis walk state: next crossing alpha after a_start, per-crossing
    // alpha increment.
    float ax0, ax1, ax2, da0, da1, da2;
    if (fabsf(sd0) < EPS) { ax0 = 3.0e38f; da0 = 0.0f; }
    else {
        float p = s0 + a_start * sd0;
        float k = (sd0 > 0.0f) ? (floorf(p) + 1.0f) : (ceilf(p) - 1.0f);
        ax0 = (k - s0) * inv0; da0 = fabsf(inv0);
    }
    if (fabsf(sd1) < EPS) { ax1 = 3.0e38f; da1 = 0.0f; }
    else {
        float p = s1 + a_start * sd1;
        float k = (sd1 > 0.0f) ? (floorf(p) + 1.0f) : (ceilf(p) - 1.0f);
        ax1 = (k - s1) * inv1; da1 = fabsf(inv1);
    }
    if (fabsf(sd2) < EPS) { ax2 = 3.0e38f; da2 = 0.0f; }
    else {
        float p = s2 + a_start * sd2;
        float k = (sd2 > 0.0f) ? (floorf(p) + 1.0f) : (ceilf(p) - 1.0f);
        ax2 = (k - s2) * inv2; da2 = fabsf(inv2);
    }

    // segment walk with a per-lane aligned-float4 cache. Each segment's voxel
    // index is recomputed from its midpoint (reference-exact; no error
    // propagation). clip(floor(p),0,255) == trunc(clamp(p,0,255)); the flat
    // index c0*65536 + c1*256 + c2 <= 2^24-1 is exact in fp32.
    float acc = 0.0f;
    float alpha = a_start;
    float4 quad = make_float4(0.f, 0.f, 0.f, 0.f);
    int qbase = -8;                                 // invalid -> first use reloads
    while (alpha < a_end) {
        float m     = fminf(fminf(ax0, ax1), ax2);  // v_min3
        float astop = fminf(m, a_end);
        float amid  = 0.5f * (alpha + astop);
        float seg   = fmaxf(astop - alpha, 0.0f);
        float c0 = truncf(fminf(fmaxf(fmaf(amid, sd0, s0), 0.0f), 255.0f));
        float c1 = truncf(fminf(fmaxf(fmaf(amid, sd1, s1), 0.0f), 255.0f));
        float c2 = truncf(fminf(fmaxf(fmaf(amid, sd2, s2), 0.0f), 255.0f));
        int idx = (int)fmaf(c0, 65536.0f, fmaf(c1, 256.0f, c2));
        int d = idx - qbase;
        if ((unsigned)d >= 4u) {                    // miss: reload aligned quad
            qbase = idx & ~3;                       // 16B-aligned, in-bounds
            quad  = *(const float4*)(density + qbase);
            d = idx - qbase;
        }
        float v = (d & 2) ? ((d & 1) ? quad.w : quad.z)
                          : ((d & 1) ? quad.y : quad.x);
        acc = fmaf(v, seg, acc);
        if (ax0 <= m) ax0 += da0;
        if (ax1 <= m) ax1 += da1;
        if (ax2 <= m) ax2 += da2;
        alpha = m;
    }

    // combine the 4 wave partials for each ray in LDS, then one atomic.
    red[tid] = acc;
    __syncthreads();
    if (tid < 64) {
        float total = red[tid] + red[tid + 64] + red[tid + 128] + red[tid + 192];
        atomicAdd(&out[ray], total * raylen);
    }
}

extern "C" void kernel_launch(void* const* d_in, const int* in_sizes, int n_in,
                              void* d_out, int out_size, void* d_ws, size_t ws_size,
                              hipStream_t stream) {
    const float* density = (const float*)d_in[0];
    const float* pose    = (const float*)d_in[1];   // [1,4,4]
    const float* ainv    = (const float*)d_in[2];   // [4,4]
    float* out = (float*)d_out;                     // [1,1,160,160] flat

    hipLaunchKernelGGL(zero_out_kernel, dim3((NRAY + 255) / 256), dim3(256), 0,
                       stream, out, NRAY);

    dim3 block(256);
    dim3 grid(NTILE * CHUNKS);                      // 3200 blocks
    hipLaunchKernelGGL(drr_siddon_kernel, grid, block, 0, stream,
                       density, pose, ainv, out);
}